// Round 1
// baseline (3913.866 us; speedup 1.0000x reference)
//
#include <hip/hip_runtime.h>

// Problem constants
#define BB   8
#define CIN  256
#define COUT 256
#define HH   64
#define WW   64
#define HW   (HH*WW)        // 4096
#define KT   9
#define KTOT (CIN*KT)       // 2304

// Workspace layout (in floats)
#define WS_OFF     0                        // [B][2][H][W] = 65536
#define WS_SCALE   (WS_OFF + BB*2*HW)       // [B][H][W]    = 32768  -> 98304
#define WS_ABSMAX  (WS_SCALE + BB*HW)       // 3 uints (absmax bits), pad to 4
#define WS_WOFFQ   (WS_ABSMAX + 4)          // [2][CIN][9] = 4608
#define WS_WSCALEQ (WS_WOFFQ + 2*KTOT)      // [CIN][9]    = 2304
#define WS_WDCNT   (WS_WSCALEQ + KTOT)      // [KTOT][COUT] transposed = 589824
#define WS_TOTAL   (WS_WDCNT + KTOT*COUT)

__device__ __forceinline__ float fq(float w, float s) {
    float q = rintf(w / s);              // round half-to-even, matches jnp.round
    q = fminf(fmaxf(q, -8.f), 7.f);      // clip(-n-1, n), n=7
    return q * s;
}

// ---------------- absmax over a tensor (atomicMax on float bits, vals >= 0) ----
__global__ void absmax_kernel(const float* __restrict__ w, int n, unsigned* out) {
    __shared__ float red[256];
    float m = 0.f;
    for (int i = blockIdx.x * blockDim.x + threadIdx.x; i < n;
         i += blockDim.x * gridDim.x)
        m = fmaxf(m, fabsf(w[i]));
    red[threadIdx.x] = m;
    __syncthreads();
    for (int s = 128; s > 0; s >>= 1) {
        if (threadIdx.x < (unsigned)s)
            red[threadIdx.x] = fmaxf(red[threadIdx.x], red[threadIdx.x + s]);
        __syncthreads();
    }
    if (threadIdx.x == 0) atomicMax(out, __float_as_uint(red[0]));
}

// ---------------- quantize w_off + w_scale ------------------------------------
__global__ void quant_small_kernel(const float* __restrict__ w_off,
                                   const float* __restrict__ w_scale,
                                   float* __restrict__ ws) {
    const unsigned* am = (const unsigned*)(ws + WS_ABSMAX);
    float s_off = fmaxf(__uint_as_float(am[0]), 1e-8f) / 7.f;
    float s_sc  = fmaxf(__uint_as_float(am[1]), 1e-8f) / 7.f;
    int t = blockIdx.x * 256 + threadIdx.x;     // 0 .. 6911
    if (t < 2 * KTOT) {
        (ws + WS_WOFFQ)[t] = fq(w_off[t], s_off);
    } else {
        int u = t - 2 * KTOT;
        (ws + WS_WSCALEQ)[u] = fq(w_scale[u], s_sc);
    }
}

// ---------------- quantize + transpose w_dcn: [o][ck] -> [ck][o] --------------
__global__ void quant_dcn_kernel(const float* __restrict__ w_dcn,
                                 float* __restrict__ ws) {
    const unsigned* am = (const unsigned*)(ws + WS_ABSMAX);
    float s = fmaxf(__uint_as_float(am[2]), 1e-8f) / 7.f;
    int t = blockIdx.x * 256 + threadIdx.x;     // 0 .. 589823
    int o  = t & 255;
    int ck = t >> 8;
    float v = w_dcn[o * KTOT + ck];
    (ws + WS_WDCNT)[ck * COUT + o] = fq(v, s);
}

// ---------------- offset/scale 3x3 conv (channel-split + atomicAdd) -----------
#define OS_CHUNK 64
__global__ __launch_bounds__(64) void offscale_kernel(const float* __restrict__ x,
                                                      float* __restrict__ ws) {
    int bx = blockIdx.x;           // (b*64 + i)*4 + chunk
    int chunk = bx & 3;
    int row = bx >> 2;
    int b = row >> 6;
    int i = row & 63;
    int j = threadIdx.x;
    const float* woq = ws + WS_WOFFQ;
    const float* wsq = ws + WS_WSCALEQ;
    float a0 = 0.f, a1 = 0.f, a2 = 0.f;
    int c0 = chunk * OS_CHUNK;
    for (int c = c0; c < c0 + OS_CHUNK; ++c) {
        const float* xb = x + (size_t)(b * CIN + c) * HW;
        const float* w0 = woq + c * 9;
        const float* w1 = woq + KTOT + c * 9;
        const float* w2 = wsq + c * 9;
#pragma unroll
        for (int di = -1; di <= 1; ++di) {
            int yy = i + di;
            bool rv = (yy >= 0) && (yy < HH);
#pragma unroll
            for (int dj = -1; dj <= 1; ++dj) {
                int xx = j + dj;
                float xv = (rv && xx >= 0 && xx < WW) ? xb[yy * WW + xx] : 0.f;
                int t = (di + 1) * 3 + (dj + 1);
                a0 += xv * w0[t];
                a1 += xv * w1[t];
                a2 += xv * w2[t];
            }
        }
    }
    atomicAdd(ws + WS_OFF + (size_t)(b * 2 + 0) * HW + i * WW + j, a0);
    atomicAdd(ws + WS_OFF + (size_t)(b * 2 + 1) * HW + i * WW + j, a1);
    atomicAdd(ws + WS_SCALE + (size_t)b * HW + i * WW + j, a2);
}

// ---------------- main fused deformable conv (implicit GEMM, fp32) ------------
// Block: one (b, i) row -> M=64 positions x N=256 out channels. 256 threads,
// each computes 8(m) x 8(n) register tile. K-loop: 2 channels x 9 taps = 18 per
// iter, A staged in double-buffered LDS; B read direct from L1/L2-resident
// transposed quantized weights.
#define KC 18
#define NITER (KTOT / KC)   // 128

__global__ __launch_bounds__(256, 2) void dcn_main_kernel(
    const float* __restrict__ x, const float* __restrict__ b_off,
    const float* __restrict__ b_scale, const float* __restrict__ b_dcn,
    const float* __restrict__ ws, float* __restrict__ out) {
    __shared__ __attribute__((aligned(16))) int   sIdx[KT][WW][4];
    __shared__ __attribute__((aligned(16))) float sWt[KT][WW][4];
    __shared__ __attribute__((aligned(16))) float sA[2][KC][WW];

    int bx = blockIdx.x;            // 0..511
    int b = bx >> 6;
    int i = bx & 63;
    int tid = threadIdx.x;
    const float* xb  = x + (size_t)b * CIN * HW;
    const float* offp = ws + WS_OFF + (size_t)(b * 2) * HW + i * WW; // ch0 row
    const float* scp  = ws + WS_SCALE + (size_t)b * HW + i * WW;
    const float* wT   = ws + WS_WDCNT;
    float bo0 = b_off[0], bo1 = b_off[1], bs = b_scale[0];

    // ---- phase 0: bilinear sampling metadata per (k, m) ----
    for (int e = tid; e < KT * WW; e += 256) {
        int m = e & 63;
        int k = e >> 6;
        float o0 = offp[m] + bo0;
        float o1 = offp[HW + m] + bo1;
        float sc = fmaxf(scp[m] + bs, 0.f);
        float ry = (float)(k / 3 - 1);
        float rx = (float)(k % 3 - 1);
        float py = (float)i + ry * sc + o0;
        float px = (float)m + rx * sc + o1;
        float y0 = floorf(py), x0 = floorf(px);
        float wy = py - y0, wx = px - x0;
#pragma unroll
        for (int cy = 0; cy < 2; ++cy)
#pragma unroll
            for (int cx = 0; cx < 2; ++cx) {
                float yf = y0 + (float)cy, xf = x0 + (float)cx;
                bool valid = (yf >= 0.f) && (yf <= 63.f) &&
                             (xf >= 0.f) && (xf <= 63.f);
                float wgt = (cy ? wy : 1.f - wy) * (cx ? wx : 1.f - wx);
                float ycl = fminf(fmaxf(yf, 0.f), 63.f);
                float xcl = fminf(fmaxf(xf, 0.f), 63.f);
                int idx = (int)ycl * WW + (int)xcl;
                int cc = cy * 2 + cx;
                sIdx[k][m][cc] = idx;
                sWt[k][m][cc] = valid ? wgt : 0.f;
            }
    }
    __syncthreads();

    int tn = tid & 31;   // n-group: o = tn*8 + ni
    int tm = tid >> 5;   // m-group: j = tm*8 + mi

    float acc[8][8];
#pragma unroll
    for (int a = 0; a < 8; ++a)
#pragma unroll
        for (int c = 0; c < 8; ++c) acc[a][c] = 0.f;

    // staging helpers (1152 samples per iter; threads 0..127 do 5, rest 4)
    auto stage_loads = [&](int c0, float pv[5][4]) {
#pragma unroll
        for (int r = 0; r < 5; ++r) {
            int e = tid + r * 256;
            if (e < KC * WW) {
                int m = e & 63;
                int kc = e >> 6;                 // 0..17
                int c = c0 + (kc >= 9 ? 1 : 0);
                int k = (kc >= 9) ? kc - 9 : kc;
                const float* xc = xb + (size_t)c * HW;
                int4 ip = *(const int4*)sIdx[k][m];
                pv[r][0] = xc[ip.x];
                pv[r][1] = xc[ip.y];
                pv[r][2] = xc[ip.z];
                pv[r][3] = xc[ip.w];
            }
        }
    };
    auto stage_store = [&](int buf, float pv[5][4]) {
#pragma unroll
        for (int r = 0; r < 5; ++r) {
            int e = tid + r * 256;
            if (e < KC * WW) {
                int m = e & 63;
                int kc = e >> 6;
                int k = (kc >= 9) ? kc - 9 : kc;
                float4 wp = *(const float4*)sWt[k][m];
                sA[buf][kc][m] = pv[r][0] * wp.x + pv[r][1] * wp.y +
                                 pv[r][2] * wp.z + pv[r][3] * wp.w;
            }
        }
    };

    // prologue: stage iter 0
    {
        float pv[5][4];
        stage_loads(0, pv);
        stage_store(0, pv);
    }
    __syncthreads();

    for (int iter = 0; iter < NITER; ++iter) {
        int cur = iter & 1;
        float pvn[5][4];
        bool has_next = (iter + 1) < NITER;
        if (has_next) stage_loads((iter + 1) * 2, pvn);  // issue loads early

        int ckg0 = iter * KC;
#pragma unroll
        for (int kc = 0; kc < KC; ++kc) {
            const float4* ap = (const float4*)&sA[cur][kc][tm * 8];
            float4 a0 = ap[0], a1 = ap[1];
            const float* bp = wT + (size_t)(ckg0 + kc) * COUT + tn * 8;
            float4 bv0 = *(const float4*)bp;
            float4 bv1 = *(const float4*)(bp + 4);
            float am8[8] = {a0.x, a0.y, a0.z, a0.w, a1.x, a1.y, a1.z, a1.w};
            float bn8[8] = {bv0.x, bv0.y, bv0.z, bv0.w,
                            bv1.x, bv1.y, bv1.z, bv1.w};
#pragma unroll
            for (int mi = 0; mi < 8; ++mi)
#pragma unroll
                for (int ni = 0; ni < 8; ++ni)
                    acc[mi][ni] += am8[mi] * bn8[ni];
        }

        if (has_next) stage_store((iter + 1) & 1, pvn);
        __syncthreads();
    }

    // ---- epilogue ----
    int j0 = tm * 8;
#pragma unroll
    for (int ni = 0; ni < 8; ++ni) {
        int o = tn * 8 + ni;
        float bb = b_dcn[o];
        float* op = out + (((size_t)(b * COUT + o)) * HH + i) * WW + j0;
        float4 s0 = {acc[0][ni] + bb, acc[1][ni] + bb,
                     acc[2][ni] + bb, acc[3][ni] + bb};
        float4 s1 = {acc[4][ni] + bb, acc[5][ni] + bb,
                     acc[6][ni] + bb, acc[7][ni] + bb};
        *(float4*)op = s0;
        *(float4*)(op + 4) = s1;
    }
}

extern "C" void kernel_launch(void* const* d_in, const int* in_sizes, int n_in,
                              void* d_out, int out_size, void* d_ws, size_t ws_size,
                              hipStream_t stream) {
    const float* x       = (const float*)d_in[0];
    const float* w_off   = (const float*)d_in[1];
    const float* b_off   = (const float*)d_in[2];
    const float* w_scale = (const float*)d_in[3];
    const float* b_scale = (const float*)d_in[4];
    const float* w_dcn   = (const float*)d_in[5];
    const float* b_dcn   = (const float*)d_in[6];
    float* out = (float*)d_out;
    float* ws  = (float*)d_ws;
    unsigned* am = (unsigned*)(ws + WS_ABSMAX);

    // zero off/scale accumulators + absmax slots
    hipMemsetAsync(d_ws, 0, (size_t)(WS_ABSMAX + 4) * sizeof(float), stream);

    absmax_kernel<<<dim3(8),   dim3(256), 0, stream>>>(w_off,   2 * KTOT, am + 0);
    absmax_kernel<<<dim3(8),   dim3(256), 0, stream>>>(w_scale, KTOT,     am + 1);
    absmax_kernel<<<dim3(256), dim3(256), 0, stream>>>(w_dcn, KTOT * COUT, am + 2);

    quant_small_kernel<<<dim3(27),   dim3(256), 0, stream>>>(w_off, w_scale, ws);
    quant_dcn_kernel<<<dim3(2304),   dim3(256), 0, stream>>>(w_dcn, ws);

    offscale_kernel<<<dim3(BB * HH * 4), dim3(64), 0, stream>>>(x, ws);

    dcn_main_kernel<<<dim3(BB * HH), dim3(256), 0, stream>>>(
        x, b_off, b_scale, b_dcn, ws, out);
}

// Round 2
// 365.801 us; speedup vs baseline: 10.6995x; 10.6995x over previous
//
#include <hip/hip_runtime.h>

// Problem constants
#define BB   8
#define CIN  256
#define COUT 256
#define HH   64
#define WW   64
#define HW   (HH*WW)        // 4096
#define KT   9
#define KTOT (CIN*KT)       // 2304
#define NKS  72             // K-steps of 32 (tap-major: k = tap*256 + c)

typedef short short8 __attribute__((ext_vector_type(8)));
typedef float f32x4  __attribute__((ext_vector_type(4)));

// Workspace layout (in floats)
#define WS_OFF     0                        // [B][2][H][W]
#define WS_SCALE   (WS_OFF + BB*2*HW)       // [B][H][W]
#define WS_ABSMAX  (WS_SCALE + BB*HW)       // 3 uints, pad 4
#define WS_WOFFQ   (WS_ABSMAX + 4)          // [2][CIN][9]
#define WS_WSCALEQ (WS_WOFFQ + 2*KTOT)      // [CIN][9]
#define WS_BQ      (WS_WSCALEQ + KTOT)      // bf16[NKS*8192] B-fragment order

__device__ __forceinline__ float fq(float w, float s) {
    float q = rintf(w / s);              // RNE, matches jnp.round
    q = fminf(fmaxf(q, -8.f), 7.f);
    return q * s;
}

__device__ __forceinline__ unsigned short f2bf(float f) {
    unsigned u = __float_as_uint(f);
    return (unsigned short)((u + 0x7fffu + ((u >> 16) & 1u)) >> 16);  // RNE
}

// ---------------- absmax (atomicMax on float bits, vals >= 0) -----------------
__global__ void absmax_kernel(const float* __restrict__ w, int n, unsigned* out) {
    __shared__ float red[256];
    float m = 0.f;
    for (int i = blockIdx.x * blockDim.x + threadIdx.x; i < n;
         i += blockDim.x * gridDim.x)
        m = fmaxf(m, fabsf(w[i]));
    red[threadIdx.x] = m;
    __syncthreads();
    for (int s = 128; s > 0; s >>= 1) {
        if (threadIdx.x < (unsigned)s)
            red[threadIdx.x] = fmaxf(red[threadIdx.x], red[threadIdx.x + s]);
        __syncthreads();
    }
    if (threadIdx.x == 0) atomicMax(out, __float_as_uint(red[0]));
}

// ---------------- quantize w_off + w_scale ------------------------------------
__global__ void quant_small_kernel(const float* __restrict__ w_off,
                                   const float* __restrict__ w_scale,
                                   float* __restrict__ ws) {
    const unsigned* am = (const unsigned*)(ws + WS_ABSMAX);
    float s_off = fmaxf(__uint_as_float(am[0]), 1e-8f) / 7.f;
    float s_sc  = fmaxf(__uint_as_float(am[1]), 1e-8f) / 7.f;
    int t = blockIdx.x * 256 + threadIdx.x;     // 0 .. 6911
    if (t < 2 * KTOT) {
        (ws + WS_WOFFQ)[t] = fq(w_off[t], s_off);
    } else {
        int u = t - 2 * KTOT;
        (ws + WS_WSCALEQ)[u] = fq(w_scale[u], s_sc);
    }
}

// -------- quantize w_dcn -> bf16 in MFMA B-fragment order ---------------------
// Bq flat t = ((((ks*16 + nt)*4 + q)*16 + ln)*8 + j)
//   o = nt*16+ln ; tap = ks>>3 ; c = (ks&7)*32 + q*8 + j
__global__ void quant_dcn_kernel(const float* __restrict__ w_dcn,
                                 float* __restrict__ ws) {
    const unsigned* am = (const unsigned*)(ws + WS_ABSMAX);
    float s = fmaxf(__uint_as_float(am[2]), 1e-8f) / 7.f;
    int t = blockIdx.x * 256 + threadIdx.x;     // < 589824
    int j  = t & 7;
    int l  = (t >> 3) & 15;
    int qq = (t >> 7) & 3;
    int nt = (t >> 9) & 15;
    int ks = t >> 13;
    int o   = nt * 16 + l;
    int tap = ks >> 3;
    int c   = ((ks & 7) << 5) + qq * 8 + j;
    float v = fq(w_dcn[(o * CIN + c) * KT + tap], s);
    ((unsigned short*)(ws + WS_BQ))[t] = f2bf(v);
}

// ---------------- offset/scale 3x3 conv (channel-split + atomicAdd) -----------
#define OS_CHUNK 64
__global__ __launch_bounds__(64) void offscale_kernel(const float* __restrict__ x,
                                                      float* __restrict__ ws) {
    int bx = blockIdx.x;           // (b*64 + i)*4 + chunk
    int chunk = bx & 3;
    int row = bx >> 2;
    int b = row >> 6;
    int i = row & 63;
    int j = threadIdx.x;
    const float* woq = ws + WS_WOFFQ;
    const float* wsq = ws + WS_WSCALEQ;
    float a0 = 0.f, a1 = 0.f, a2 = 0.f;
    int c0 = chunk * OS_CHUNK;
    for (int c = c0; c < c0 + OS_CHUNK; ++c) {
        const float* xb = x + (size_t)(b * CIN + c) * HW;
        const float* w0 = woq + c * 9;
        const float* w1 = woq + KTOT + c * 9;
        const float* w2 = wsq + c * 9;
#pragma unroll
        for (int di = -1; di <= 1; ++di) {
            int yy = i + di;
            bool rv = (yy >= 0) && (yy < HH);
#pragma unroll
            for (int dj = -1; dj <= 1; ++dj) {
                int xx = j + dj;
                float xv = (rv && xx >= 0 && xx < WW) ? xb[yy * WW + xx] : 0.f;
                int t = (di + 1) * 3 + (dj + 1);
                a0 += xv * w0[t];
                a1 += xv * w1[t];
                a2 += xv * w2[t];
            }
        }
    }
    atomicAdd(ws + WS_OFF + (size_t)(b * 2 + 0) * HW + i * WW + j, a0);
    atomicAdd(ws + WS_OFF + (size_t)(b * 2 + 1) * HW + i * WW + j, a1);
    atomicAdd(ws + WS_SCALE + (size_t)b * HW + i * WW + j, a2);
}

// ---------------- main fused deformable conv: MFMA bf16 implicit GEMM ---------
// Block = (b, row i): M=64 pixels x N=256 outs, K=2304 tap-major, 72 K-steps.
// 4 waves; wave w: m-tiles 0..3 x n-tiles {4w..4w+3} -> 16 MFMA/K-step, acc=64.
// A sampled on the fly (wave w computes channels c0+8w..+8 for all 64 pixels ->
// single-plane gathers), shared via LDS. B double-buffered via global_load_lds.
struct Meta { int o0, o1; float e0, e1, e2, e3; };

__global__ __launch_bounds__(256, 2) void dcn_main_kernel(
    const float* __restrict__ x, const float* __restrict__ b_off,
    const float* __restrict__ b_scale, const float* __restrict__ b_dcn,
    const float* __restrict__ ws, float* __restrict__ out) {
    __shared__ Meta   sMeta[KT][WW];            // 13824 B
    __shared__ short8 sA[2][4][4][16];          // [buf][mt][q][lm] : 8192 B
    __shared__ short8 sB[2][16][4][16];         // [buf][nt][q][ln] : 32768 B

    const int tid = threadIdx.x;
    const int b = blockIdx.x >> 6;
    const int i = blockIdx.x & 63;
    const int w  = tid >> 6;      // wave id = n-group = sampling channel-group
    const int m  = tid & 63;      // lane = sampling pixel
    const int q  = m >> 4;        // MFMA quad
    const int ln = m & 15;        // MFMA lane-within-16

    const float* xb = x + (size_t)b * CIN * HW;
    const unsigned short* Bq = (const unsigned short*)(ws + WS_BQ);

    // ---- phase 0: bilinear metadata per (tap, pixel) ----
    {
        const float* offp = ws + WS_OFF + (size_t)(b * 2) * HW + i * WW;
        const float* scp  = ws + WS_SCALE + (size_t)b * HW + i * WW;
        float bo0 = b_off[0], bo1 = b_off[1], bs = b_scale[0];
        for (int e = tid; e < KT * WW; e += 256) {
            int mm = e & 63, k = e >> 6;
            float o0 = offp[mm] + bo0;
            float o1 = offp[HW + mm] + bo1;
            float sc = fmaxf(scp[mm] + bs, 0.f);
            float ry = (float)(k / 3 - 1), rx = (float)(k % 3 - 1);
            float py = (float)i + ry * sc + o0;
            float px = (float)mm + rx * sc + o1;
            float y0f = floorf(py), x0f = floorf(px);
            float wy = py - y0f, wx = px - x0f;
            float w00 = (1.f - wy) * (1.f - wx), w01 = (1.f - wy) * wx;
            float w10 = wy * (1.f - wx),         w11 = wy * wx;
            bool vy0 = (y0f >= 0.f)  && (y0f <= 63.f);
            bool vy1 = (y0f >= -1.f) && (y0f <= 62.f);
            bool vx0 = (x0f >= 0.f)  && (x0f <= 63.f);
            bool vx1 = (x0f >= -1.f) && (x0f <= 62.f);
            bool d0hi = x0f > 62.f;   // x0 corner maps to slot +1 (x0==63)
            bool d1lo = x0f < 0.f;    // x0+1 corner maps to slot 0 (x0==-1)
            float e0 = 0.f, e1 = 0.f, e2 = 0.f, e3 = 0.f;
            if (vy0 && vx0) { if (d0hi) e1 += w00; else e0 += w00; }
            if (vy0 && vx1) { if (d1lo) e0 += w01; else e1 += w01; }
            if (vy1 && vx0) { if (d0hi) e3 += w10; else e2 += w10; }
            if (vy1 && vx1) { if (d1lo) e2 += w11; else e3 += w11; }
            int r0 = (int)fminf(fmaxf(y0f, 0.f), 63.f);
            int r1 = (int)fminf(fmaxf(y0f + 1.f, 0.f), 63.f);
            int cb = (int)fminf(fmaxf(x0f, 0.f), 62.f);
            Meta mt_;
            mt_.o0 = r0 * WW + cb; mt_.o1 = r1 * WW + cb;
            mt_.e0 = e0; mt_.e1 = e1; mt_.e2 = e2; mt_.e3 = e3;
            sMeta[k][mm] = mt_;
        }
    }

    // ---- helpers ----
    auto sampleA = [&](int ks, float v[8]) {
        int tap = ks >> 3;
        int cg = ((ks & 7) << 5) + w * 8;       // first of 8 channels
        Meta mt_ = sMeta[tap][m];
        const float* pl = xb + (size_t)cg * HW;
#pragma unroll
        for (int j = 0; j < 8; ++j) {
            const float* p0 = pl + j * HW + mt_.o0;
            const float* p1 = pl + j * HW + mt_.o1;
            float a0 = p0[0], a1 = p0[1], a2 = p1[0], a3 = p1[1];
            v[j] = mt_.e0 * a0 + mt_.e1 * a1 + mt_.e2 * a2 + mt_.e3 * a3;
        }
    };
    auto writeA = [&](int buf, float v[8]) {
        short8 pk;
#pragma unroll
        for (int j = 0; j < 8; ++j) pk[j] = (short)f2bf(v[j]);
        sA[buf][m >> 4][w][m & 15] = pk;        // one ds_write_b128
    };
    auto stageB = [&](int ks, int buf) {
#pragma unroll
        for (int r = 0; r < 4; ++r) {
            const unsigned short* g = Bq + (size_t)ks * 8192 + r * 2048 + tid * 8;
            __builtin_amdgcn_global_load_lds(
                (const __attribute__((address_space(1))) void*)g,
                (__attribute__((address_space(3))) void*)
                    ((char*)&sB[buf][0][0][0] + r * 4096 + w * 1024),
                16, 0, 0);
        }
    };

    // ---- prologue ----
    stageB(0, 0);
    {
        float v0_[8];
        sampleA(0, v0_);
        writeA(0, v0_);
    }
    __syncthreads();

    f32x4 acc[4][4];
#pragma unroll
    for (int a = 0; a < 4; ++a)
#pragma unroll
        for (int c = 0; c < 4; ++c) acc[a][c] = (f32x4){0.f, 0.f, 0.f, 0.f};

    // ---- K-loop ----
    for (int it = 0; it < NKS; ++it) {
        int cur = it & 1, nxt = cur ^ 1;
        bool hn = (it + 1) < NKS;
        if (hn) stageB(it + 1, nxt);
        float vn[8];
        if (hn) sampleA(it + 1, vn);

        short8 af0 = sA[cur][0][q][ln];
        short8 af1 = sA[cur][1][q][ln];
        short8 af2 = sA[cur][2][q][ln];
        short8 af3 = sA[cur][3][q][ln];
#pragma unroll
        for (int ntl = 0; ntl < 4; ++ntl) {
            short8 bf = sB[cur][w * 4 + ntl][q][ln];
            acc[0][ntl] = __builtin_amdgcn_mfma_f32_16x16x32_bf16(af0, bf, acc[0][ntl], 0, 0, 0);
            acc[1][ntl] = __builtin_amdgcn_mfma_f32_16x16x32_bf16(af1, bf, acc[1][ntl], 0, 0, 0);
            acc[2][ntl] = __builtin_amdgcn_mfma_f32_16x16x32_bf16(af2, bf, acc[2][ntl], 0, 0, 0);
            acc[3][ntl] = __builtin_amdgcn_mfma_f32_16x16x32_bf16(af3, bf, acc[3][ntl], 0, 0, 0);
        }
        if (hn) writeA(nxt, vn);
        __syncthreads();
    }

    // ---- epilogue: transpose via LDS (reuse sB region, per-wave private) ----
    {
        float* T = ((float*)sB) + w * (16 * 68);
        int row = (tid & 63) >> 2;
        int seg = tid & 3;
#pragma unroll
        for (int ntl = 0; ntl < 4; ++ntl) {
            int nt = w * 4 + ntl;
            float bias = b_dcn[nt * 16 + ln];
#pragma unroll
            for (int mt2 = 0; mt2 < 4; ++mt2)
#pragma unroll
                for (int r = 0; r < 4; ++r)
                    T[ln * 68 + mt2 * 16 + q * 4 + r] = acc[mt2][ntl][r] + bias;
            int o = nt * 16 + row;
            float* ob = out + (((size_t)(b * COUT + o)) * HH + i) * WW + seg * 16;
#pragma unroll
            for (int u = 0; u < 4; ++u) {
                f32x4 val = *(f32x4*)&T[row * 68 + seg * 16 + u * 4];
                *(f32x4*)(ob + u * 4) = val;
            }
        }
    }
}

extern "C" void kernel_launch(void* const* d_in, const int* in_sizes, int n_in,
                              void* d_out, int out_size, void* d_ws, size_t ws_size,
                              hipStream_t stream) {
    const float* x       = (const float*)d_in[0];
    const float* w_off   = (const float*)d_in[1];
    const float* b_off   = (const float*)d_in[2];
    const float* w_scale = (const float*)d_in[3];
    const float* b_scale = (const float*)d_in[4];
    const float* w_dcn   = (const float*)d_in[5];
    const float* b_dcn   = (const float*)d_in[6];
    float* out = (float*)d_out;
    float* ws  = (float*)d_ws;
    unsigned* am = (unsigned*)(ws + WS_ABSMAX);

    // zero off/scale accumulators + absmax slots
    hipMemsetAsync(d_ws, 0, (size_t)(WS_ABSMAX + 4) * sizeof(float), stream);

    absmax_kernel<<<dim3(8),   dim3(256), 0, stream>>>(w_off,   2 * KTOT, am + 0);
    absmax_kernel<<<dim3(8),   dim3(256), 0, stream>>>(w_scale, KTOT,     am + 1);
    absmax_kernel<<<dim3(256), dim3(256), 0, stream>>>(w_dcn, KTOT * COUT, am + 2);

    quant_small_kernel<<<dim3(27),   dim3(256), 0, stream>>>(w_off, w_scale, ws);
    quant_dcn_kernel<<<dim3(2304),   dim3(256), 0, stream>>>(w_dcn, ws);

    offscale_kernel<<<dim3(BB * HH * 4), dim3(64), 0, stream>>>(x, ws);

    dcn_main_kernel<<<dim3(BB * HH), dim3(256), 0, stream>>>(
        x, b_off, b_scale, b_dcn, ws, out);
}

// Round 3
// 343.361 us; speedup vs baseline: 11.3987x; 1.0654x over previous
//
#include <hip/hip_runtime.h>

// Problem constants
#define BB   8
#define CIN  256
#define COUT 256
#define HH   64
#define WW   64
#define HW   (HH*WW)        // 4096
#define KT   9
#define KTOT (CIN*KT)       // 2304
#define NKS  72             // K-steps of 32 (tap-major: k = tap*256 + c)

typedef short short8 __attribute__((ext_vector_type(8)));
typedef float f32x4  __attribute__((ext_vector_type(4)));
typedef float f32x2  __attribute__((ext_vector_type(2)));

// Workspace layout (float offsets)
#define WS_OFF     0            // [B][2][HW] = 65536
#define WS_SCALE   65536        // [B][HW]    = 32768
#define WS_PART    98304        // 64 partial absmax of w_dcn
#define WS_SDCN    98368        // 1 float (s_dcn), pad
#define WS_WOFFQ   98372        // [2][CIN][9] = 4608
#define WS_WSCALEQ 102980       // [CIN][9]    = 2304
#define WS_BQ      105284       // fp8 bytes [NKS*2*64*64] = 589824 B (byte addr %16==0)

#define USE_FP8_HW __has_builtin(__builtin_amdgcn_cvt_pk_f32_fp8)

__device__ __forceinline__ float fq(float w, float s) {
    float q = rintf(w / s);              // RNE, matches jnp.round
    q = fminf(fmaxf(q, -8.f), 7.f);
    return q * s;
}

__device__ __forceinline__ unsigned short f2bf(float f) {
    unsigned u = __float_as_uint(f);
    return (unsigned short)((u + 0x7fffu + ((u >> 16) & 1u)) >> 16);  // RNE
}

// =============== K1: absmax partials + small-tensor quant =====================
__global__ __launch_bounds__(256) void prep_kernel(const float* __restrict__ w_dcn,
                                                   const float* __restrict__ w_off,
                                                   const float* __restrict__ w_scale,
                                                   float* __restrict__ ws) {
    __shared__ float red[256];
    const int bx = blockIdx.x, tid = threadIdx.x;
    if (bx < 64) {                       // partial absmax of w_dcn
        float m = 0.f;
        const float* p = w_dcn + bx * 9216;
#pragma unroll
        for (int k = 0; k < 36; ++k) m = fmaxf(m, fabsf(p[tid + k * 256]));
        red[tid] = m;
        __syncthreads();
        for (int s = 128; s > 0; s >>= 1) {
            if (tid < s) red[tid] = fmaxf(red[tid], red[tid + s]);
            __syncthreads();
        }
        if (tid == 0) ws[WS_PART + bx] = red[0];
    } else {                             // small tensors: absmax + quantize
        const float* src = (bx == 64) ? w_off : w_scale;
        const int n = (bx == 64) ? 2 * KTOT : KTOT;
        float* dst = ws + ((bx == 64) ? WS_WOFFQ : WS_WSCALEQ);
        float m = 0.f;
        for (int i = tid; i < n; i += 256) m = fmaxf(m, fabsf(src[i]));
        red[tid] = m;
        __syncthreads();
        for (int s = 128; s > 0; s >>= 1) {
            if (tid < s) red[tid] = fmaxf(red[tid], red[tid + s]);
            __syncthreads();
        }
        float sq = fmaxf(red[0], 1e-8f) / 7.f;
        for (int i = tid; i < n; i += 256) dst[i] = fq(src[i], sq);
    }
}

// =============== K2: offset/scale conv + w_dcn quant to fp8-int ===============
__global__ __launch_bounds__(256) void mid_kernel(const float* __restrict__ x,
                                                  const float* __restrict__ w_dcn,
                                                  float* __restrict__ ws) {
    __shared__ float R[4][3][64];
    const int bx = blockIdx.x, tid = threadIdx.x;
    if (bx < 512) {
        // ---- offset/scale 3x3 conv, one (b,i) row per block ----
        const int b = bx & 7, i = bx >> 3;
        const int j = tid & 63, cq = tid >> 6;
        const float* woq = ws + WS_WOFFQ;
        const float* wsq = ws + WS_WSCALEQ;
        float a0 = 0.f, a1 = 0.f, a2 = 0.f;
        for (int c = cq * 64; c < cq * 64 + 64; ++c) {
            const float* xb = x + (size_t)(b * CIN + c) * HW;
            const float* w0 = woq + c * 9;
            const float* w1 = woq + KTOT + c * 9;
            const float* w2 = wsq + c * 9;
#pragma unroll
            for (int di = -1; di <= 1; ++di) {
                int yy = i + di;
                bool rv = (yy >= 0) && (yy < HH);
#pragma unroll
                for (int dj = -1; dj <= 1; ++dj) {
                    int xx = j + dj;
                    float xv = (rv && xx >= 0 && xx < WW) ? xb[yy * WW + xx] : 0.f;
                    int t = (di + 1) * 3 + (dj + 1);
                    a0 += xv * w0[t];
                    a1 += xv * w1[t];
                    a2 += xv * w2[t];
                }
            }
        }
        R[cq][0][j] = a0; R[cq][1][j] = a1; R[cq][2][j] = a2;
        __syncthreads();
        if (tid < 192) {
            int comp = tid >> 6, j2 = tid & 63;
            float v = R[0][comp][j2] + R[1][comp][j2] +
                      R[2][comp][j2] + R[3][comp][j2];
            if (comp == 0)      ws[WS_OFF + (b * 2 + 0) * HW + i * WW + j2] = v;
            else if (comp == 1) ws[WS_OFF + (b * 2 + 1) * HW + i * WW + j2] = v;
            else                ws[WS_SCALE + b * HW + i * WW + j2] = v;
        }
    } else {
        // ---- quantize w_dcn -> stream of integer-valued fp8 bytes ----
        const int qb = bx - 512;          // 0..575
        float m = 0.f;
#pragma unroll
        for (int k = 0; k < 64; ++k) m = fmaxf(m, ws[WS_PART + k]);
        float s = fmaxf(m, 1e-8f) / 7.f;
        if (qb == 0 && tid == 0) ws[WS_SDCN] = s;
        const int t4 = (qb * 256 + tid) * 4;
        float qv[4];
#pragma unroll
        for (int u = 0; u < 4; ++u) {
            int t = t4 + u;
            int j  = t & 7;
            int f  = (t >> 3) & 7;
            int l  = (t >> 6) & 63;
            int wn = (t >> 12) & 1;
            int ks = t >> 13;
            int q = l >> 4, ln = l & 15;
            int nt = wn * 8 + f;
            int o = nt * 16 + ln;
            int tap = ks >> 3;
            int c = ((ks & 7) << 5) + q * 8 + j;
            float w = w_dcn[(o * CIN + c) * KT + tap];
            qv[u] = fminf(fmaxf(rintf(w / s), -8.f), 7.f);
        }
        unsigned d;
#if USE_FP8_HW
        d = 0;
        d = __builtin_amdgcn_cvt_pk_fp8_f32(qv[0], qv[1], d, false);
        d = __builtin_amdgcn_cvt_pk_fp8_f32(qv[2], qv[3], d, true);
#else
        d = ((unsigned)(unsigned char)(signed char)(int)qv[0])
          | ((unsigned)(unsigned char)(signed char)(int)qv[1] << 8)
          | ((unsigned)(unsigned char)(signed char)(int)qv[2] << 16)
          | ((unsigned)(unsigned char)(signed char)(int)qv[3] << 24);
#endif
        ((unsigned*)(ws + WS_BQ))[qb * 256 + tid] = d;
    }
}

// =============== K3: main fused deformable conv (MFMA bf16) ===================
// Block = (b, row-pair): M=128 px x N=256 outs, 512 thr / 8 waves, grid 256.
// Wave roles: sampling: row = w&1, ch-quad = w>>1. compute: m-group g=w>>1
// (m-tiles 2g,2g+1), n-half wn=w&1 (n-tiles wn*8..+8). 16 MFMA/wave/K-step.
// B: per-lane contiguous 64 fp8 bytes/K-step, global->reg, decode 1 op/wt.
// A: gathered + bilinear (s_dcn folded into weights), bf16-packed, dbuf LDS.
struct Meta { int o0, o1; float e0, e1, e2, e3; };
union SharedU {
    struct { Meta meta[KT][2][64]; short8 a[2][8][4][16]; } s;  // 27648+16384
    float T[8][16][33];                                          // epilogue
};
union FragU { short8 s; unsigned u[4]; };

__device__ __forceinline__ void cvt4(unsigned d, unsigned& p0, unsigned& p1) {
#if USE_FP8_HW
    f32x2 lo = __builtin_amdgcn_cvt_pk_f32_fp8(d, false);
    f32x2 hi = __builtin_amdgcn_cvt_pk_f32_fp8(d, true);
    p0 = __builtin_amdgcn_perm(__float_as_uint(lo.y), __float_as_uint(lo.x),
                               0x07060302u);
    p1 = __builtin_amdgcn_perm(__float_as_uint(hi.y), __float_as_uint(hi.x),
                               0x07060302u);
#else
    float f0 = (float)(int)(signed char)(d & 0xff);
    float f1 = (float)(int)(signed char)((d >> 8) & 0xff);
    float f2 = (float)(int)(signed char)((d >> 16) & 0xff);
    float f3 = (float)(int)(signed char)(d >> 24);
    p0 = __builtin_amdgcn_perm(__float_as_uint(f1), __float_as_uint(f0),
                               0x07060302u);
    p1 = __builtin_amdgcn_perm(__float_as_uint(f3), __float_as_uint(f2),
                               0x07060302u);
#endif
}

__global__ __launch_bounds__(512) void dcn_main_kernel(
    const float* __restrict__ x, const float* __restrict__ b_off,
    const float* __restrict__ b_scale, const float* __restrict__ b_dcn,
    const float* __restrict__ ws, float* __restrict__ out) {
    __shared__ SharedU sh;
    const int tid = threadIdx.x;
    const int bx = blockIdx.x;
    const int b = bx & 7;            // XCD-swizzle: batch b -> XCD b
    const int i0 = (bx >> 3) * 2;    // row pair
    const int w = tid >> 6, l = tid & 63;

    const float* xb = x + (size_t)b * CIN * HW;
    const char* Bq = (const char*)(ws + WS_BQ);
    const float sdcn = ws[WS_SDCN];

    // ---- bilinear metadata (s_dcn folded into corner weights) ----
    {
        float bo0 = b_off[0], bo1 = b_off[1], bs = b_scale[0];
        for (int e = tid; e < KT * 128; e += 512) {
            int mm = e & 63, row = (e >> 6) & 1, tap = e >> 7;
            int i = i0 + row;
            float o0 = ws[WS_OFF + (b * 2 + 0) * HW + i * WW + mm] + bo0;
            float o1 = ws[WS_OFF + (b * 2 + 1) * HW + i * WW + mm] + bo1;
            float sc = fmaxf(ws[WS_SCALE + b * HW + i * WW + mm] + bs, 0.f);
            float ry = (float)(tap / 3 - 1), rx = (float)(tap % 3 - 1);
            float py = (float)i + ry * sc + o0;
            float px = (float)mm + rx * sc + o1;
            float y0f = floorf(py), x0f = floorf(px);
            float wy = py - y0f, wx = px - x0f;
            float w00 = (1.f - wy) * (1.f - wx), w01 = (1.f - wy) * wx;
            float w10 = wy * (1.f - wx),         w11 = wy * wx;
            bool vy0 = (y0f >= 0.f)  && (y0f <= 63.f);
            bool vy1 = (y0f >= -1.f) && (y0f <= 62.f);
            bool vx0 = (x0f >= 0.f)  && (x0f <= 63.f);
            bool vx1 = (x0f >= -1.f) && (x0f <= 62.f);
            bool d0hi = x0f > 62.f;
            bool d1lo = x0f < 0.f;
            float e0 = 0.f, e1 = 0.f, e2 = 0.f, e3 = 0.f;
            if (vy0 && vx0) { if (d0hi) e1 += w00; else e0 += w00; }
            if (vy0 && vx1) { if (d1lo) e0 += w01; else e1 += w01; }
            if (vy1 && vx0) { if (d0hi) e3 += w10; else e2 += w10; }
            if (vy1 && vx1) { if (d1lo) e2 += w11; else e3 += w11; }
            int r0 = (int)fminf(fmaxf(y0f, 0.f), 63.f);
            int r1 = (int)fminf(fmaxf(y0f + 1.f, 0.f), 63.f);
            int cb = (int)fminf(fmaxf(x0f, 0.f), 62.f);
            Meta mt_;
            mt_.o0 = r0 * WW + cb; mt_.o1 = r1 * WW + cb;
            mt_.e0 = e0 * sdcn; mt_.e1 = e1 * sdcn;
            mt_.e2 = e2 * sdcn; mt_.e3 = e3 * sdcn;
            sh.s.meta[tap][row][mm] = mt_;
        }
    }

    // sampling roles
    const int srow = w & 1, scg = w >> 1;
    const int smt = srow * 4 + (l >> 4), sln = l & 15;
    // compute roles
    const int g = w >> 1, wn = w & 1;

    auto sampleA = [&](int ks, float v[8]) {
        int tap = ks >> 3;
        Meta mt_ = sh.s.meta[tap][srow][l];
        int c0 = ((ks & 7) << 5) + scg * 8;
        const float* pl = xb + (size_t)c0 * HW;
#pragma unroll
        for (int jj = 0; jj < 8; ++jj) {
            const float* p0 = pl + jj * HW + mt_.o0;
            const float* p1 = pl + jj * HW + mt_.o1;
            v[jj] = mt_.e0 * p0[0] + mt_.e1 * p0[1] +
                    mt_.e2 * p1[0] + mt_.e3 * p1[1];
        }
    };
    auto writeA = [&](int buf, float v[8]) {
        short8 pk;
#pragma unroll
        for (int jj = 0; jj < 8; ++jj) pk[jj] = (short)f2bf(v[jj]);
        sh.s.a[buf][smt][scg][sln] = pk;
    };
    auto loadBraw = [&](int ks, uint4 r[4]) {
        const uint4* p = (const uint4*)(Bq + ((size_t)(ks * 2 + wn) * 64 + l) * 64);
        r[0] = p[0]; r[1] = p[1]; r[2] = p[2]; r[3] = p[3];
    };
    auto convB = [&](uint4 raw[4], FragU bf[8]) {
#pragma unroll
        for (int f = 0; f < 8; ++f) {
            uint4 rr = raw[f >> 1];
            unsigned d0 = (f & 1) ? rr.z : rr.x;
            unsigned d1 = (f & 1) ? rr.w : rr.y;
            cvt4(d0, bf[f].u[0], bf[f].u[1]);
            cvt4(d1, bf[f].u[2], bf[f].u[3]);
        }
    };

    // ---- prologue: stage step 0 ----
    uint4 rawB[4];
    FragU curBf[8];
    loadBraw(0, rawB);
    {
        float v0_[8];
        sampleA(0, v0_);
        writeA(0, v0_);
    }
    convB(rawB, curBf);
    __syncthreads();

    f32x4 acc[2][8];
#pragma unroll
    for (int a = 0; a < 2; ++a)
#pragma unroll
        for (int f = 0; f < 8; ++f) acc[a][f] = (f32x4){0.f, 0.f, 0.f, 0.f};

    // ---- K-loop ----
    for (int it = 0; it < NKS; ++it) {
        const int cur = it & 1;
        const bool hn = (it + 1) < NKS;
        float vs[8];
        if (hn) loadBraw(it + 1, rawB);   // B: global->reg, no barrier dep
        if (hn) sampleA(it + 1, vs);      // A gathers issued early

        short8 af0 = sh.s.a[cur][g * 2 + 0][l >> 4][l & 15];
        short8 af1 = sh.s.a[cur][g * 2 + 1][l >> 4][l & 15];
#pragma unroll
        for (int f = 0; f < 8; ++f) {
            acc[0][f] = __builtin_amdgcn_mfma_f32_16x16x32_bf16(
                af0, curBf[f].s, acc[0][f], 0, 0, 0);
            acc[1][f] = __builtin_amdgcn_mfma_f32_16x16x32_bf16(
                af1, curBf[f].s, acc[1][f], 0, 0, 0);
        }
        if (hn) convB(rawB, curBf);       // overwrite after MFMAs consumed
        if (hn) writeA(cur ^ 1, vs);
        __syncthreads();
    }

    // ---- epilogue: per-wave LDS transpose, coalesced float4 stores ----
    {
        float* T = &sh.T[w][0][0];
        const int rowg = g >> 1;          // waves g=0,1 -> row0 ; 2,3 -> row1
        const int i_out = i0 + rowg;
        const int jbase = (g & 1) * 32;
        const int oc_l = l >> 2, seg = l & 3;
#pragma unroll
        for (int f = 0; f < 8; ++f) {
#pragma unroll
            for (int a2 = 0; a2 < 2; ++a2)
#pragma unroll
                for (int r = 0; r < 4; ++r)
                    T[(l & 15) * 33 + a2 * 16 + (l >> 4) * 4 + r] = acc[a2][f][r];
            int oc = (wn * 8 + f) * 16 + oc_l;
            float bb = b_dcn[oc];
            float* op = out + (((size_t)(b * COUT + oc)) * HH + i_out) * WW +
                        jbase + seg * 8;
            f32x4 v0, v1;
#pragma unroll
            for (int u = 0; u < 4; ++u) v0[u] = T[oc_l * 33 + seg * 8 + u] + bb;
#pragma unroll
            for (int u = 0; u < 4; ++u) v1[u] = T[oc_l * 33 + seg * 8 + 4 + u] + bb;
            *(f32x4*)op = v0;
            *(f32x4*)(op + 4) = v1;
        }
    }
}

extern "C" void kernel_launch(void* const* d_in, const int* in_sizes, int n_in,
                              void* d_out, int out_size, void* d_ws, size_t ws_size,
                              hipStream_t stream) {
    const float* x       = (const float*)d_in[0];
    const float* w_off   = (const float*)d_in[1];
    const float* b_off   = (const float*)d_in[2];
    const float* w_scale = (const float*)d_in[3];
    const float* b_scale = (const float*)d_in[4];
    const float* w_dcn   = (const float*)d_in[5];
    const float* b_dcn   = (const float*)d_in[6];
    float* out = (float*)d_out;
    float* ws  = (float*)d_ws;

    prep_kernel<<<dim3(66),   dim3(256), 0, stream>>>(w_dcn, w_off, w_scale, ws);
    mid_kernel <<<dim3(1088), dim3(256), 0, stream>>>(x, w_dcn, ws);
    dcn_main_kernel<<<dim3(256), dim3(512), 0, stream>>>(
        x, b_off, b_scale, b_dcn, ws, out);
}